// Round 5
// baseline (612.666 us; speedup 1.0000x reference)
//
#include <hip/hip_runtime.h>
#include <cstdint>
#include <cstddef>

#define NN 4096
#define ITERS 50
#define TB 256            // tile is TB x TB
#define TSTRIDE 264       // halves per LDS tile row (16B-aligned rows)
#define NBLK 256          // 16 x 16 blocks
#define NTHR 1024
#define SLOT (16 * NN)    // floats per exchange slot: 16 groups x 16 x 256

typedef _Float16 half4v __attribute__((ext_vector_type(4)));
typedef _Float16 half8v __attribute__((ext_vector_type(8)));

#define T_BYTES (TB * TSTRIDE * 2)                      // 135168
#define RED_FLOATS 4096                                 // red[16][256]
#define SMEM_BYTES (T_BYTES + RED_FLOATS * 4 + 1024 + 1024)   // 153600

#define SCOPE __HIP_MEMORY_SCOPE_AGENT

// ---------------------------------------------------------------------------
// Cooperative LDS-resident Sinkhorn, DATA-IS-FLAG exchange with SIGN-
// GENERATION tagging (no atomic RMW, no flag indirection, no resets):
//   Partials are strictly positive -> encode the generation in the sign.
//   Slot = it&1 (2 slots/buffer, each SLOT=16*NN floats); stored value =
//   s * sgn, sgn alternates every reuse of a slot: sgn(it) = ((it>>1)&1).
//   Writers: one relaxed agent-scope store of +/-s (fire-and-forget).
//   Readers: poll the 16 partial words for the EXPECTED SIGN; stale values
//   (previous generation of this slot) have the opposite sign and are
//   rejected; 0.0f (zeroed per launch) fails both sign tests.
//   Overwrite-before-read is impossible: a writer reaching generation it+2
//   must first observe this reader's generation-(it+1) store (poll chains
//   through every block of the shared group), which the reader issues only
//   after its generation-(it) poll completed; per-location LLC coherence
//   then orders the overwrite after the read.
//   |value| is exact (sign flip preserves mantissa) -> summation bitwise
//   identical to round-0's flag protocol.
// ROUND 2-4 BUG (fixed here): slot stride was NN instead of 16*NN ->
//   every block wrote up to 4x past d_ws -> GPU fault -> harness crash.
// Watchdog: polls give up after 2^20 spins so a protocol stall terminates
//   with wrong output (diagnosable) instead of hanging the harness.
// Barriers: 4 per iteration (round 0 had ~8 + 2 flag legs per exchange).
// ---------------------------------------------------------------------------

__global__ void sk_zero(float* __restrict__ b) {
    size_t i = (size_t)blockIdx.x * blockDim.x + threadIdx.x;
    __hip_atomic_store(&b[i], 0.0f, __ATOMIC_RELAXED, SCOPE);
}

__device__ __forceinline__ float pload(const float* p) {
    return __hip_atomic_load(p, __ATOMIC_RELAXED, SCOPE);
}
__device__ __forceinline__ void pstore(float* p, float v) {
    __hip_atomic_store(p, v, __ATOMIC_RELAXED, SCOPE);
}

// Poll 16 partials at src[g*256 + t] until each has the expected sign
// (neg ? v<0 : v>0); own_g's value comes from a register (positive, raw).
// Returns sum of |vals| in ascending g order (bitwise == untagged sum).
__device__ __forceinline__ float poll_sum16(const float* __restrict__ src,
                                            int own_g, float own_v, int t,
                                            bool neg) {
    float vals[16];
    #pragma unroll
    for (int g = 0; g < 16; ++g)
        vals[g] = (g == own_g) ? own_v : pload(&src[g * 256 + t]);
    unsigned miss = 0;
    #pragma unroll
    for (int g = 0; g < 16; ++g) {
        bool ok = neg ? (vals[g] < 0.0f) : (vals[g] > 0.0f);
        if (g != own_g && !ok) miss |= (1u << g);
    }
    int guard = 1 << 20;   // watchdog: stall -> wrong-but-terminating run
    while (miss && --guard) {
        __builtin_amdgcn_s_sleep(1);
        #pragma unroll
        for (int g = 0; g < 16; ++g)
            if (miss & (1u << g)) {
                float v = pload(&src[g * 256 + t]);
                vals[g] = v;
                bool ok = neg ? (v < 0.0f) : (v > 0.0f);
                if (ok) miss &= ~(1u << g);
            }
    }
    float s = 0.0f;
    #pragma unroll
    for (int g = 0; g < 16; ++g) s += fabsf(vals[g]);
    return s;
}

__global__ __launch_bounds__(NTHR) void sk_coop(const float* __restrict__ M,
                                                float* __restrict__ out,
                                                float* __restrict__ rbuf,
                                                float* __restrict__ cbuf) {
    extern __shared__ char smem[];
    _Float16* T   = (_Float16*)smem;               // [TB][TSTRIDE]
    float*    red = (float*)(smem + T_BYTES);      // [16][256]
    float*    rcv = red + RED_FLOATS;              // [256]
    float*    rrv = rcv + 256;                     // [256]

    const int t  = threadIdx.x;
    const int bi = blockIdx.x >> 4;    // row group
    const int bj = blockIdx.x & 15;    // col group
    const float* Mt = M + ((size_t)bi * TB) * NN + (size_t)bj * TB;

    // ---- load tile: E = exp(M) -> fp16 LDS ----
    #pragma unroll
    for (int i = 0; i < 16; ++i) {
        int idx = t + i * NTHR;
        int r = idx >> 6, c4 = idx & 63;
        float4 m = *(const float4*)(Mt + (size_t)r * NN + c4 * 4);
        half4v h;
        h[0] = (_Float16)__expf(m.x);
        h[1] = (_Float16)__expf(m.y);
        h[2] = (_Float16)__expf(m.z);
        h[3] = (_Float16)__expf(m.w);
        *(half4v*)&T[r * TSTRIDE + c4 * 4] = h;
    }

    float my_cp = 0.0f;   // this thread's col partial (raw, positive)

    for (int it = 0; it < ITERS; ++it) {
        const float tag  = (((unsigned)it >> 1) & 1u) ? -1.0f : 1.0f;
        const bool  sneg = (((unsigned)it >> 1) & 1u) != 0u;

        // ---- stage 1: rcv from col partials of it-1 (sign-tagged poll) ----
        if (it == 0) {
            if (t < TB) rcv[t] = 1.0f;
        } else {
            if (t < TB) {
                const bool pneg = (((unsigned)(it - 1) >> 1) & 1u) != 0u;
                const float* src = cbuf + (size_t)((it - 1) & 1) * SLOT
                                 + (size_t)bj * (16 * TB);
                rcv[t] = 1.0f / poll_sum16(src, bi, my_cp, t, pneg);
            }
        }
        __syncthreads();

        // ---- phase A: row sums. thread: row = t&255, q = t>>8 owns 64 cols ----
        {
            const int row = t & 255, q = t >> 8;
            const half8v* Trow = (const half8v*)&T[row * TSTRIDE + q * 64];
            const float4* rc4  = (const float4*)(rcv + q * 64);
            float s = 0.0f;
            #pragma unroll
            for (int k = 0; k < 8; ++k) {
                half8v hv = Trow[k];
                float4 c0 = rc4[2 * k];
                float4 c1 = rc4[2 * k + 1];
                s += (float)hv[0] * c0.x + (float)hv[1] * c0.y +
                     (float)hv[2] * c0.z + (float)hv[3] * c0.w +
                     (float)hv[4] * c1.x + (float)hv[5] * c1.y +
                     (float)hv[6] * c1.z + (float)hv[7] * c1.w;
            }
            red[q * 256 + row] = s;
        }
        __syncthreads();

        // ---- stage 2: row exchange (store +/-s -> poll peers, own from reg) ----
        if (t < TB) {
            float s = red[t] + red[256 + t] + red[512 + t] + red[768 + t];
            float* rb = rbuf + (size_t)(it & 1) * SLOT;
            pstore(&rb[((size_t)bi * 16 + bj) * TB + t], s * tag);
            rrv[t] = 1.0f / poll_sum16(rb + (size_t)bi * (16 * TB), bj, s, t,
                                       sneg);
        }
        __syncthreads();

        // ---- phase B: col sums. ch = t&31 (8 cols), sub = t>>5 (8 rows) ----
        {
            const int ch = t & 31, sub = t >> 5;
            const int w = t >> 6, lane = t & 63;
            float acc[8] = {0, 0, 0, 0, 0, 0, 0, 0};
            #pragma unroll
            for (int r = 0; r < 8; ++r) {
                const int row = sub * 8 + r;
                half8v hv = *(const half8v*)&T[row * TSTRIDE + ch * 8];
                float rr = rrv[row];
                #pragma unroll
                for (int j = 0; j < 8; ++j) acc[j] += (float)hv[j] * rr;
            }
            #pragma unroll
            for (int j = 0; j < 8; ++j) acc[j] += __shfl_down(acc[j], 32);
            if (lane < 32) {
                const int rot = (lane >> 2) & 7;
                float* rd = red + w * 256 + ch * 8;
                #pragma unroll
                for (int jj = 0; jj < 8; ++jj) {
                    int j = (jj + rot) & 7;
                    rd[j] = acc[j];
                }
            }
        }
        __syncthreads();

        // ---- stage 3: col partial store (fire-and-forget; polled at it+1) ----
        if (t < TB) {
            float s = 0.0f;
            #pragma unroll
            for (int w = 0; w < 16; ++w) s += red[w * 256 + t];
            my_cp = s;
            pstore(&cbuf[(size_t)(it & 1) * SLOT
                         + ((size_t)bj * 16 + bi) * TB + t], s * tag);
        }
        // no barrier: next stage-1 poll touches no LDS that stage 3 reads;
        // next phase-A red writes are fenced by the post-stage-1 barrier.
    }

    // ---- epilogue: poll final col partials; out = max(exp(M)*rr*rc, 1e-9) ----
    if (t < TB) {
        const bool pneg = (((unsigned)(ITERS - 1) >> 1) & 1u) != 0u;
        const float* src = cbuf + (size_t)((ITERS - 1) & 1) * SLOT
                         + (size_t)bj * (16 * TB);
        rcv[t] = 1.0f / poll_sum16(src, bi, my_cp, t, pneg);
    }
    __syncthreads();

    float* outt = out + ((size_t)bi * TB) * NN + (size_t)bj * TB;
    #pragma unroll
    for (int i = 0; i < 16; ++i) {
        int idx = t + i * NTHR;
        int r = idx >> 6, c4 = idx & 63;
        float4 m = *(const float4*)(Mt + (size_t)r * NN + c4 * 4);
        float rr = rrv[r];
        float4 c = ((const float4*)rcv)[c4];
        float4 o;
        o.x = fmaxf(__expf(m.x) * rr * c.x, 1e-9f);
        o.y = fmaxf(__expf(m.y) * rr * c.y, 1e-9f);
        o.z = fmaxf(__expf(m.z) * rr * c.z, 1e-9f);
        o.w = fmaxf(__expf(m.w) * rr * c.w, 1e-9f);
        *(float4*)(outt + (size_t)r * NN + c4 * 4) = o;
    }
}

// ===========================================================================
// Fallback multi-kernel path (round-1, known-good).
// ===========================================================================

__global__ __launch_bounds__(256) void sk_init(float* __restrict__ rc,
                                               float* __restrict__ c_sum) {
    int j = blockIdx.x * 256 + threadIdx.x;
    rc[j] = 1.0f;
    c_sum[j] = 0.0f;
}

__global__ __launch_bounds__(256) void sk_exp(const float* __restrict__ M,
                                              float* __restrict__ E) {
    size_t idx = ((size_t)blockIdx.x * 256 + threadIdx.x) * 4;
    float4 m = *(const float4*)(M + idx);
    float4 e;
    e.x = __expf(m.x); e.y = __expf(m.y); e.z = __expf(m.z); e.w = __expf(m.w);
    *(float4*)(E + idx) = e;
}

template<bool HAS_E>
__global__ __launch_bounds__(256) void sk_row(const float* __restrict__ Mat,
                                              const float* __restrict__ rc,
                                              float* __restrict__ rr) {
    const int wave = threadIdx.x >> 6;
    const int lane = threadIdx.x & 63;
    const int row  = blockIdx.x * 4 + wave;
    const float4* __restrict__ Mrow = (const float4*)(Mat + (size_t)row * NN);
    const float4* __restrict__ RC   = (const float4*)rc;
    float s = 0.0f;
    #pragma unroll 4
    for (int k = lane; k < NN / 4; k += 64) {
        float4 m = Mrow[k];
        float4 c = RC[k];
        if (!HAS_E) {
            m.x = __expf(m.x); m.y = __expf(m.y);
            m.z = __expf(m.z); m.w = __expf(m.w);
        }
        s += m.x * c.x + m.y * c.y + m.z * c.z + m.w * c.w;
    }
    #pragma unroll
    for (int off = 32; off > 0; off >>= 1) s += __shfl_down(s, off, 64);
    if (lane == 0) rr[row] = 1.0f / s;
}

template<bool HAS_E>
__global__ __launch_bounds__(256) void sk_col(const float* __restrict__ Mat,
                                              const float* __restrict__ rr,
                                              float* __restrict__ c_sum) {
    const int j  = blockIdx.x * 256 + threadIdx.x;
    const int r0 = blockIdx.y * 64;
    const float* __restrict__ rrp = rr + r0;
    const float* __restrict__ p   = Mat + (size_t)r0 * NN + j;
    float s = 0.0f;
    #pragma unroll 8
    for (int i = 0; i < 64; ++i) {
        float m = p[(size_t)i * NN];
        if (!HAS_E) m = __expf(m);
        s += m * rrp[i];
    }
    atomicAdd(&c_sum[j], s);
}

__global__ __launch_bounds__(256) void sk_recip(float* __restrict__ c_sum,
                                                float* __restrict__ rc) {
    int j = blockIdx.x * 256 + threadIdx.x;
    rc[j] = 1.0f / c_sum[j];
    c_sum[j] = 0.0f;
}

template<bool HAS_E>
__global__ __launch_bounds__(256) void sk_final(const float* __restrict__ Mat,
                                                const float* __restrict__ rr,
                                                const float* __restrict__ rc,
                                                float* __restrict__ out) {
    const int row = blockIdx.y;
    const int c4  = blockIdx.x * 256 + threadIdx.x;
    float4 m = ((const float4*)(Mat + (size_t)row * NN))[c4];
    if (!HAS_E) {
        m.x = __expf(m.x); m.y = __expf(m.y);
        m.z = __expf(m.z); m.w = __expf(m.w);
    }
    float4 c = ((const float4*)rc)[c4];
    float  r = rr[row];
    float4 o;
    o.x = fmaxf(m.x * r * c.x, 1e-9f);
    o.y = fmaxf(m.y * r * c.y, 1e-9f);
    o.z = fmaxf(m.z * r * c.z, 1e-9f);
    o.w = fmaxf(m.w * r * c.w, 1e-9f);
    ((float4*)out)[(size_t)row * (NN / 4) + c4] = o;
}

static void launch_fallback(const float* M, float* out, char* ws, size_t ws_size,
                            hipStream_t stream) {
    float* rc    = (float*)(ws);
    float* rr    = (float*)(ws + 16 * 1024);
    float* c_sum = (float*)(ws + 32 * 1024);
    float* E     = (float*)(ws + 64 * 1024);

    const size_t need_e = 64 * 1024 + (size_t)NN * NN * sizeof(float);
    const bool   has_e  = ws_size >= need_e;

    sk_init<<<NN / 256, 256, 0, stream>>>(rc, c_sum);

    const float* Mat = M;
    if (has_e) {
        sk_exp<<<(NN * (size_t)NN) / 1024, 256, 0, stream>>>(M, E);
        Mat = E;
    }

    dim3 gcol(16, 64);
    for (int it = 0; it < ITERS; ++it) {
        if (has_e) sk_row<true ><<<NN / 4, 256, 0, stream>>>(Mat, rc, rr);
        else       sk_row<false><<<NN / 4, 256, 0, stream>>>(Mat, rc, rr);
        if (has_e) sk_col<true ><<<gcol, 256, 0, stream>>>(Mat, rr, c_sum);
        else       sk_col<false><<<gcol, 256, 0, stream>>>(Mat, rr, c_sum);
        sk_recip<<<NN / 256, 256, 0, stream>>>(c_sum, rc);
    }

    dim3 gfin(4, NN);
    if (has_e) sk_final<true ><<<gfin, 256, 0, stream>>>(Mat, rr, rc, out);
    else       sk_final<false><<<gfin, 256, 0, stream>>>(Mat, rr, rc, out);
}

extern "C" void kernel_launch(void* const* d_in, const int* in_sizes, int n_in,
                              void* d_out, int out_size, void* d_ws, size_t ws_size,
                              hipStream_t stream) {
    const float* M   = (const float*)d_in[0];
    float*       out = (float*)d_out;
    char*        ws  = (char*)d_ws;

    // coop-path workspace: rbuf[2][SLOT] f32 | cbuf[2][SLOT] f32  (1 MiB)
    float* rbuf = (float*)ws;
    float* cbuf = rbuf + (size_t)2 * SLOT;
    const size_t ws_need = (size_t)4 * SLOT * sizeof(float);

    int dev = 0;
    (void)hipGetDevice(&dev);
    int coop = 0;
    (void)hipDeviceGetAttribute(&coop, hipDeviceAttributeCooperativeLaunch, dev);
    hipError_t eattr = hipFuncSetAttribute(
        (const void*)sk_coop, hipFuncAttributeMaxDynamicSharedMemorySize, SMEM_BYTES);

    bool done = false;
    if (coop && eattr == hipSuccess && ws_size >= ws_need) {
        // zero both buffers: 4*SLOT floats = 262144 = 256 blocks x 1024
        sk_zero<<<256, 1024, 0, stream>>>(rbuf);
        void* args[4] = {(void*)&M, (void*)&out, (void*)&rbuf, (void*)&cbuf};
        hipError_t e = hipLaunchCooperativeKernel((void*)sk_coop, dim3(NBLK),
                                                  dim3(NTHR), args, SMEM_BYTES,
                                                  stream);
        done = (e == hipSuccess);
    }
    if (!done) launch_fallback(M, out, ws, ws_size, stream);
}